// Round 1
// 439.500 us; speedup vs baseline: 1.0676x; 1.0676x over previous
//
#include <hip/hip_runtime.h>
#include <hip/hip_bf16.h>

#define BT 1024
#define DD 1024
#define HH 2048
#define OO 1024
#define EE 8
#define RMAX 3072   // max padded rows (1024 tokens * 2 assignments, padded per expert)

typedef __bf16 bf16x8 __attribute__((ext_vector_type(8)));
typedef float  f32x4  __attribute__((ext_vector_type(4)));

// async global -> LDS, 16 bytes per lane. LDS dest must be wave-uniform base + lane*16.
__device__ __forceinline__ void cp16(void* l, const void* g) {
    __builtin_amdgcn_global_load_lds(
        (const __attribute__((address_space(1))) void*)g,
        (__attribute__((address_space(3))) void*)l, 16, 0, 0);
}

// ---------------- workspace layout (bytes) ----------------
// counts : int[8]              @ 0
// off    : int[9]              @ 256
// tok_e  : int[2048]           @ 1024
// tok_p  : int[2048]           @ 9216
// tok_w  : float[2048]         @ 17408
// elist  : int[8*1024]         @ 25600
// Xg     : bf16[3072*1024]     @ 65536       (end 6356992)
// H1     : bf16[3072*2048]     @ 6356992     (end 18939904)
// H2     : bf16[3072*2048]     @ 18939904    (end 31522816)
// Y      : f32 [3072*1024]     @ 31522816    (end 44105728)

// ---------------- router: logits -> softmax -> top2 -> renorm ----------------
__global__ __launch_bounds__(256) void router_kernel(
    const float* __restrict__ x, const float* __restrict__ Wr, const float* __restrict__ br,
    int* __restrict__ counts, int* __restrict__ elist,
    int* __restrict__ tok_e, int* __restrict__ tok_p, float* __restrict__ tok_w)
{
    int b = blockIdx.x;
    int tid = threadIdx.x;
    float acc[EE];
#pragma unroll
    for (int e = 0; e < EE; ++e) acc[e] = 0.f;
    const float* xr = x + (size_t)b * DD;
    for (int d = tid; d < DD; d += 256) {
        float xv = xr[d];
#pragma unroll
        for (int e = 0; e < EE; ++e) acc[e] += xv * Wr[d * EE + e];
    }
    __shared__ float red[4][EE];
    int lane = tid & 63, wv = tid >> 6;
#pragma unroll
    for (int e = 0; e < EE; ++e) {
        float v = acc[e];
#pragma unroll
        for (int o = 32; o > 0; o >>= 1) v += __shfl_down(v, o, 64);
        if (lane == 0) red[wv][e] = v;
    }
    __syncthreads();
    if (tid == 0) {
        float lg[EE];
#pragma unroll
        for (int e = 0; e < EE; ++e) lg[e] = red[0][e] + red[1][e] + red[2][e] + red[3][e] + br[e];
        float mx = lg[0];
#pragma unroll
        for (int e = 1; e < EE; ++e) mx = fmaxf(mx, lg[e]);
        float s = 0.f, p[EE];
#pragma unroll
        for (int e = 0; e < EE; ++e) { p[e] = expf(lg[e] - mx); s += p[e]; }
        float inv = 1.f / s;
#pragma unroll
        for (int e = 0; e < EE; ++e) p[e] *= inv;
        int i0 = 0; float b0 = p[0];
#pragma unroll
        for (int e = 1; e < EE; ++e) if (p[e] > b0) { b0 = p[e]; i0 = e; }
        int i1 = -1; float b1v = -1.f;
#pragma unroll
        for (int e = 0; e < EE; ++e) if (e != i0 && p[e] > b1v) { b1v = p[e]; i1 = e; }
        float s2 = b0 + b1v + 1e-6f;
        float w0 = b0 / s2, w1 = b1v / s2;
        int p0 = atomicAdd(&counts[i0], 1);
        int p1 = atomicAdd(&counts[i1], 1);
        elist[i0 * 1024 + p0] = b;
        elist[i1 * 1024 + p1] = b;
        tok_e[2 * b] = i0; tok_e[2 * b + 1] = i1;
        tok_p[2 * b] = p0; tok_p[2 * b + 1] = p1;
        tok_w[2 * b] = w0; tok_w[2 * b + 1] = w1;
    }
}

// ---------------- padded prefix sum ----------------
__global__ void offsets_kernel(const int* __restrict__ counts, int* __restrict__ off)
{
    if (threadIdx.x == 0 && blockIdx.x == 0) {
        int a = 0;
        for (int e = 0; e < EE; ++e) {
            off[e] = a;
            a += ((counts[e] + 127) >> 7) << 7;
        }
        off[EE] = a;
    }
}

// ---------------- gather x rows -> bf16, pad rows zeroed ----------------
__global__ __launch_bounds__(256) void gather_kernel(
    const float* __restrict__ x, const int* __restrict__ counts, const int* __restrict__ off,
    const int* __restrict__ elist, __bf16* __restrict__ Xg)
{
    int e = blockIdx.y;
    int chunk = blockIdx.x >> 2;
    int rg = blockIdx.x & 3;
    int cnt = counts[e];
    if (chunk * 128 >= cnt) return;
    int base = off[e] + chunk * 128 + rg * 32;
    int tid = threadIdx.x;
    for (int it = 0; it < 32; ++it) {
        int slot = chunk * 128 + rg * 32 + it;
        __bf16 v[4];
        if (slot < cnt) {
            int tok = elist[e * 1024 + slot];
            const float4 f = *(const float4*)(x + (size_t)tok * DD + tid * 4);
            v[0] = (__bf16)f.x; v[1] = (__bf16)f.y; v[2] = (__bf16)f.z; v[3] = (__bf16)f.w;
        } else {
            v[0] = v[1] = v[2] = v[3] = (__bf16)0.f;
        }
        *(uint2*)(Xg + (size_t)(base + it) * DD + tid * 4) = *(uint2*)v;
    }
}

// ---------------- fused full-K MFMA GEMM: Out = act(A * W[e] + bias) ----------------
// TM=128, TN=64 or 32, BK=32. No split-K: bias (+ReLU) fused in epilogue.
// Double-buffered: next tile's A (cp16->LDS) and B (fp32->regs) issued before
// computing current tile; the __syncthreads vmcnt(0) drain is the pipeline sync.
// Grid: x = nt*8 + e (expert fastest => expert e pinned to XCD e), y = mt.
template <int K, int N, int TN, bool RELU, bool OUT_BF16>
__global__ __launch_bounds__(256) void gemm_fused(
    const __bf16* __restrict__ A, const float* __restrict__ Wall,
    const float* __restrict__ bias, void* __restrict__ OutV,
    const int* __restrict__ counts, const int* __restrict__ off)
{
    constexpr int NSTEPS = K / 32;
    constexpr int NJ  = TN / 32;   // 2 (TN=64) or 1 (TN=32)
    constexpr int BLD = TN / 8;    // B fp32 loads per thread per step: 8 or 4

    int e  = blockIdx.x & 7;
    int nt = blockIdx.x >> 3;
    int mt = blockIdx.y;
    int cnt = counts[e];
    if (mt * 128 >= cnt) return;
    int row0 = off[e] + mt * 128;

    const __bf16* Ab = A + (size_t)row0 * K;
    const float*  Wp = Wall + (size_t)e * K * N + nt * TN;

    __shared__ __bf16 As[2][128 * 32];   // [m][k] contiguous (DMA lane order)
    __shared__ __bf16 Bs[2][TN * 40];    // [n][k] stride 40 (80B rows: bank-spread, 16B-aligned)

    int tid = threadIdx.x;
    int wave = tid >> 6, lane = tid & 63;
    int m = lane & 15, q = lane >> 4;
    int wm = (wave >> 1) * 64, wn = (wave & 1) * (TN / 2);

    // A-DMA mapping: LDS byte addr = wave-uniform + lane*16
    int ar = wave * 16 + (lane >> 2);
    int k8 = (lane & 3) * 8;
    // B-stage mapping: thread owns column bn, BLD consecutive k's
    int bn  = (TN == 64) ? (tid & 63) : (tid & 31);
    int bkc = (TN == 64) ? ((tid >> 6) * 8) : ((tid >> 5) * 4);

    float breg[BLD];
    f32x4 acc[4][NJ] = {};

    auto issueA = [&](int t, int buf) {
        const __bf16* src = Ab + t * 32;
        cp16(&As[buf][ar * 32 + k8],        src + (size_t)ar * K + k8);
        cp16(&As[buf][(64 + ar) * 32 + k8], src + (size_t)(64 + ar) * K + k8);
    };
    auto loadB = [&](int t) {
        const float* p = Wp + (size_t)(t * 32 + bkc) * N + bn;
#pragma unroll
        for (int g = 0; g < BLD; ++g) breg[g] = p[(size_t)g * N];
    };
    auto writeB = [&](int buf) {
        __bf16 t8[BLD];
#pragma unroll
        for (int g = 0; g < BLD; ++g) t8[g] = (__bf16)breg[g];
        if constexpr (TN == 64) *(uint4*)(&Bs[buf][bn * 40 + bkc]) = *(uint4*)t8;
        else                    *(uint2*)(&Bs[buf][bn * 40 + bkc]) = *(uint2*)t8;
    };

    // prologue: tile 0
    issueA(0, 0);
    loadB(0);
    __syncthreads();   // drains vmcnt(0): A(0) in LDS, breg ready
    writeB(0);
    __syncthreads();

    for (int t = 0; t < NSTEPS; ++t) {
        int cur = t & 1;
        if (t + 1 < NSTEPS) {      // issue next tile before computing current
            issueA(t + 1, cur ^ 1);
            loadB(t + 1);
        }
        bf16x8 af[4], bfr[NJ];
#pragma unroll
        for (int i = 0; i < 4; ++i)
            af[i] = *(bf16x8*)(&As[cur][(wm + i * 16 + m) * 32 + q * 8]);
#pragma unroll
        for (int j = 0; j < NJ; ++j)
            bfr[j] = *(bf16x8*)(&Bs[cur][(wn + j * 16 + m) * 40 + q * 8]);
#pragma unroll
        for (int i = 0; i < 4; ++i)
#pragma unroll
            for (int j = 0; j < NJ; ++j)
                acc[i][j] = __builtin_amdgcn_mfma_f32_16x16x32_bf16(af[i], bfr[j], acc[i][j], 0, 0, 0);
        if (t + 1 < NSTEPS) {
            __syncthreads();       // all waves done reading cur; A(t+1)/breg drained
            writeB(cur ^ 1);
            __syncthreads();
        }
    }

    // epilogue: bias (+relu), store. D[row=q*4+r][col=m] per 16x16 subtile.
    const float* bp = bias + (size_t)e * N;
    int colbase = nt * TN + wn;
#pragma unroll
    for (int j = 0; j < NJ; ++j) {
        int col = colbase + j * 16 + m;
        float bv = bp[col];
#pragma unroll
        for (int i = 0; i < 4; ++i) {
            int rbase = row0 + wm + i * 16 + q * 4;
#pragma unroll
            for (int r = 0; r < 4; ++r) {
                float v = acc[i][j][r] + bv;
                if constexpr (RELU) v = fmaxf(v, 0.f);
                if constexpr (OUT_BF16)
                    ((__bf16*)OutV)[(size_t)(rbase + r) * N + col] = (__bf16)v;
                else
                    ((float*)OutV)[(size_t)(rbase + r) * N + col] = v;
            }
        }
    }
}

// ---------------- combine: out[b] = w0 * Y[r0] + w1 * Y[r1] (b3 folded into GEMM3) ----------------
__global__ __launch_bounds__(256) void combine_kernel(
    const float* __restrict__ Y, const int* __restrict__ off,
    const int* __restrict__ tok_e, const int* __restrict__ tok_p,
    const float* __restrict__ tok_w, float* __restrict__ out)
{
    int b = blockIdx.x, t = threadIdx.x;
    int e0 = tok_e[2 * b], e1 = tok_e[2 * b + 1];
    int r0 = off[e0] + tok_p[2 * b];
    int r1 = off[e1] + tok_p[2 * b + 1];
    float w0 = tok_w[2 * b], w1 = tok_w[2 * b + 1];
    int col = t * 4;
    f32x4 s0 = *(const f32x4*)(Y + (size_t)r0 * OO + col);
    f32x4 s1 = *(const f32x4*)(Y + (size_t)r1 * OO + col);
    f32x4 o = s0 * w0 + s1 * w1;
    *(f32x4*)(out + (size_t)b * OO + col) = o;
}

extern "C" void kernel_launch(void* const* d_in, const int* in_sizes, int n_in,
                              void* d_out, int out_size, void* d_ws, size_t ws_size,
                              hipStream_t stream)
{
    (void)in_sizes; (void)n_in; (void)out_size; (void)ws_size;
    const float* x  = (const float*)d_in[0];
    const float* Wr = (const float*)d_in[1];
    const float* br = (const float*)d_in[2];
    const float* W1 = (const float*)d_in[3];
    const float* b1 = (const float*)d_in[4];
    const float* W2 = (const float*)d_in[5];
    const float* b2 = (const float*)d_in[6];
    const float* W3 = (const float*)d_in[7];
    const float* b3 = (const float*)d_in[8];
    float* out = (float*)d_out;

    char* ws = (char*)d_ws;
    int*    counts = (int*)(ws + 0);
    int*    off    = (int*)(ws + 256);
    int*    tok_e  = (int*)(ws + 1024);
    int*    tok_p  = (int*)(ws + 9216);
    float*  tok_w  = (float*)(ws + 17408);
    int*    elist  = (int*)(ws + 25600);
    __bf16* Xg     = (__bf16*)(ws + 65536);
    __bf16* H1     = (__bf16*)(ws + 6356992);
    __bf16* H2     = (__bf16*)(ws + 18939904);
    float*  Y      = (float*)(ws + 31522816);

    hipMemsetAsync(counts, 0, 256, stream);
    router_kernel<<<1024, 256, 0, stream>>>(x, Wr, br, counts, elist, tok_e, tok_p, tok_w);
    offsets_kernel<<<1, 64, 0, stream>>>(counts, off);
    gather_kernel<<<dim3(32, 8), 256, 0, stream>>>(x, counts, off, elist, Xg);

    // full-K fused GEMMs: grid x = nt*8 + e (expert -> XCD pinning), y = mt (up to 1024 rows/expert)
    gemm_fused<1024, 2048, 64, true,  true ><<<dim3(256, 8), 256, 0, stream>>>(Xg, W1, b1, (void*)H1, counts, off);
    gemm_fused<2048, 2048, 64, true,  true ><<<dim3(256, 8), 256, 0, stream>>>(H1, W2, b2, (void*)H2, counts, off);
    gemm_fused<2048, 1024, 32, false, false><<<dim3(256, 8), 256, 0, stream>>>(H2, W3, b3, (void*)Y,  counts, off);

    combine_kernel<<<1024, 256, 0, stream>>>(Y, off, tok_e, tok_p, tok_w, out);
}

// Round 2
// 432.997 us; speedup vs baseline: 1.0836x; 1.0150x over previous
//
#include <hip/hip_runtime.h>
#include <hip/hip_bf16.h>

#define BT 1024
#define DD 1024
#define HH 2048
#define OO 1024
#define EE 8
#define RMAX 3072   // max padded rows (1024 tokens * 2 assignments, padded per expert)

typedef __bf16 bf16x8 __attribute__((ext_vector_type(8)));
typedef float  f32x4  __attribute__((ext_vector_type(4)));

// async global -> LDS, 16 bytes per lane. LDS dest must be wave-uniform base + lane*16.
__device__ __forceinline__ void cp16(void* l, const void* g) {
    __builtin_amdgcn_global_load_lds(
        (const __attribute__((address_space(1))) void*)g,
        (__attribute__((address_space(3))) void*)l, 16, 0, 0);
}

#define VMW(n)  asm volatile("s_waitcnt vmcnt(" #n ")" ::: "memory")
#define LGKM(n) asm volatile("s_waitcnt lgkmcnt(" #n ")" ::: "memory")
#define SCHED0  __builtin_amdgcn_sched_barrier(0)
#define BAR()   __builtin_amdgcn_s_barrier()

// ---------------- workspace layout (bytes) ----------------
// counts : int[8]              @ 0
// off    : int[9]              @ 256
// tok_e  : int[2048]           @ 1024
// tok_p  : int[2048]           @ 9216
// tok_w  : float[2048]         @ 17408
// elist  : int[8*1024]         @ 25600
// Xg     : bf16[3072*1024]     @ 65536       (end 6356992)
// H1     : bf16[3072*2048]     @ 6356992     (end 18939904)
// H2     : bf16[3072*2048]     @ 18939904    (end 31522816)
// Y      : f32 [3072*1024]     @ 31522816    (end 44105728)

// ---------------- router ----------------
__global__ __launch_bounds__(256) void router_kernel(
    const float* __restrict__ x, const float* __restrict__ Wr, const float* __restrict__ br,
    int* __restrict__ counts, int* __restrict__ elist,
    int* __restrict__ tok_e, int* __restrict__ tok_p, float* __restrict__ tok_w)
{
    int b = blockIdx.x;
    int tid = threadIdx.x;
    float acc[EE];
#pragma unroll
    for (int e = 0; e < EE; ++e) acc[e] = 0.f;
    const float* xr = x + (size_t)b * DD;
    for (int d = tid; d < DD; d += 256) {
        float xv = xr[d];
#pragma unroll
        for (int e = 0; e < EE; ++e) acc[e] += xv * Wr[d * EE + e];
    }
    __shared__ float red[4][EE];
    int lane = tid & 63, wv = tid >> 6;
#pragma unroll
    for (int e = 0; e < EE; ++e) {
        float v = acc[e];
#pragma unroll
        for (int o = 32; o > 0; o >>= 1) v += __shfl_down(v, o, 64);
        if (lane == 0) red[wv][e] = v;
    }
    __syncthreads();
    if (tid == 0) {
        float lg[EE];
#pragma unroll
        for (int e = 0; e < EE; ++e) lg[e] = red[0][e] + red[1][e] + red[2][e] + red[3][e] + br[e];
        float mx = lg[0];
#pragma unroll
        for (int e = 1; e < EE; ++e) mx = fmaxf(mx, lg[e]);
        float s = 0.f, p[EE];
#pragma unroll
        for (int e = 0; e < EE; ++e) { p[e] = expf(lg[e] - mx); s += p[e]; }
        float inv = 1.f / s;
#pragma unroll
        for (int e = 0; e < EE; ++e) p[e] *= inv;
        int i0 = 0; float b0 = p[0];
#pragma unroll
        for (int e = 1; e < EE; ++e) if (p[e] > b0) { b0 = p[e]; i0 = e; }
        int i1 = -1; float b1v = -1.f;
#pragma unroll
        for (int e = 0; e < EE; ++e) if (e != i0 && p[e] > b1v) { b1v = p[e]; i1 = e; }
        float s2 = b0 + b1v + 1e-6f;
        float w0 = b0 / s2, w1 = b1v / s2;
        int p0 = atomicAdd(&counts[i0], 1);
        int p1 = atomicAdd(&counts[i1], 1);
        elist[i0 * 1024 + p0] = b;
        elist[i1 * 1024 + p1] = b;
        tok_e[2 * b] = i0; tok_e[2 * b + 1] = i1;
        tok_p[2 * b] = p0; tok_p[2 * b + 1] = p1;
        tok_w[2 * b] = w0; tok_w[2 * b + 1] = w1;
    }
}

// ---------------- padded prefix sum ----------------
__global__ void offsets_kernel(const int* __restrict__ counts, int* __restrict__ off)
{
    if (threadIdx.x == 0 && blockIdx.x == 0) {
        int a = 0;
        for (int e = 0; e < EE; ++e) {
            off[e] = a;
            a += ((counts[e] + 127) >> 7) << 7;
        }
        off[EE] = a;
    }
}

// ---------------- gather x rows -> bf16, pad rows zeroed ----------------
__global__ __launch_bounds__(256) void gather_kernel(
    const float* __restrict__ x, const int* __restrict__ counts, const int* __restrict__ off,
    const int* __restrict__ elist, __bf16* __restrict__ Xg)
{
    int e = blockIdx.y;
    int chunk = blockIdx.x >> 2;
    int rg = blockIdx.x & 3;
    int cnt = counts[e];
    if (chunk * 128 >= cnt) return;
    int base = off[e] + chunk * 128 + rg * 32;
    int tid = threadIdx.x;
    for (int it = 0; it < 32; ++it) {
        int slot = chunk * 128 + rg * 32 + it;
        __bf16 v[4];
        if (slot < cnt) {
            int tok = elist[e * 1024 + slot];
            const float4 f = *(const float4*)(x + (size_t)tok * DD + tid * 4);
            v[0] = (__bf16)f.x; v[1] = (__bf16)f.y; v[2] = (__bf16)f.z; v[3] = (__bf16)f.w;
        } else {
            v[0] = v[1] = v[2] = v[3] = (__bf16)0.f;
        }
        *(uint2*)(Xg + (size_t)(base + it) * DD + tid * 4) = *(uint2*)v;
    }
}

// ---------------- fused full-K MFMA GEMM: Out = act(A * W[e] + bias) ----------------
// TM=128, TN=64/32, BK=64. Counted-vmcnt pipeline (T3/T4):
//  - A: 3 LDS buffers, global_load_lds prefetch distance 2, XOR-swizzled (T2,
//    linear DMA dest + pre-swizzled global source + swizzled ds_read).
//  - B: fp32->bf16 reg-staged at distance 2 (two reg sets), LDS double buffer,
//    XOR-swizzled writes/reads.
//  - ONE raw s_barrier per K-step; s_waitcnt vmcnt(4+BLD) before the B ds_write
//    keeps the newest step's 4 cp16 + BLD B-loads in flight across the barrier.
// Grid: x = nt*8 + e (expert -> XCD pinning), y = mt.
template <int K, int N, int TN, bool RELU, bool OUT_BF16>
__global__ __launch_bounds__(256, 2) void gemm_fused(
    const __bf16* __restrict__ A, const float* __restrict__ Wall,
    const float* __restrict__ bias, void* __restrict__ OutV,
    const int* __restrict__ counts, const int* __restrict__ off)
{
    constexpr int NSTEPS = K / 64;
    constexpr int NJ  = TN / 32;       // 2 (TN=64) or 1 (TN=32)
    constexpr int BLD = TN / 4;        // B fp32 loads per thread per step: 16 or 8
    constexpr int BSE = TN * 64;       // Bs elems per buffer

    int e  = blockIdx.x & 7;
    int nt = blockIdx.x >> 3;
    int mt = blockIdx.y;
    int cnt = counts[e];
    if (mt * 128 >= cnt) return;
    int row0 = off[e] + mt * 128;

    const __bf16* Ab = A + (size_t)row0 * K;
    const float*  Wp = Wall + (size_t)e * K * N + nt * TN;

    __shared__ __bf16 As[3 * 8192];    // 3 bufs, [128 rows][64 k], 128B rows, swizzled
    __shared__ __bf16 Bs[2 * BSE];     // 2 bufs, [TN rows][64 k], swizzled

    int tid = threadIdx.x;
    int wave = tid >> 6, lane = tid & 63;
    int m = lane & 15, q = lane >> 4;
    int wm = (wave >> 1) * 64, wn = (wave & 1) * (TN / 2);

    // A-DMA: lane writes LDS chunk (lane&7) of row (i*32 + wave*8 + lane>>3);
    // source pre-swizzled so LDS[r][c] holds global chunk c^(r&7).
    int rdma = wave * 8 + (lane >> 3);
    int kxe  = ((lane & 7) ^ (lane >> 3)) * 8;   // source elem offset (swizzled chunk)
    // B-stage: thread owns column bn, BLD consecutive k's starting at bkc
    int bn  = (TN == 64) ? (tid & 63) : (tid & 31);
    int bkc = (TN == 64) ? ((tid >> 6) * 16) : ((tid >> 5) * 8);
    int c0  = bkc >> 3;                // first 16B chunk index of this thread's k-range
    int bswz = bn & 7;

    float bA[BLD], bB[BLD];
    f32x4 acc[4][NJ] = {};

    auto issueA = [&](int t, unsigned ab) {
#pragma unroll
        for (int i = 0; i < 4; ++i)
            cp16(&As[ab + i * 2048 + wave * 512 + lane * 8],
                 Ab + (size_t)(i * 32 + rdma) * K + t * 64 + kxe);
    };
    auto loadB = [&](int t, float (&br_)[BLD]) {
        const float* p = Wp + (size_t)(t * 64 + bkc) * N + bn;
#pragma unroll
        for (int g = 0; g < BLD; ++g) br_[g] = p[(size_t)g * N];
    };
    auto writeB = [&](unsigned bb, float (&br_)[BLD]) {
        __bf16 t8[BLD];
#pragma unroll
        for (int g = 0; g < BLD; ++g) t8[g] = (__bf16)br_[g];
        *(uint4*)(&Bs[bb + bn * 64 + ((c0    ) ^ bswz) * 8]) = ((const uint4*)t8)[0];
        if constexpr (TN == 64)
            *(uint4*)(&Bs[bb + bn * 64 + ((c0 + 1) ^ bswz) * 8]) = ((const uint4*)t8)[1];
    };

    auto STEP = [&](int t, unsigned aR, unsigned aW, unsigned bR, unsigned bW,
                    float (&bWr)[BLD], float (&bLd)[BLD]) {
        BAR(); SCHED0;
        bool pf = (t + 2 < NSTEPS);
        if (pf) { issueA(t + 2, aW); loadB(t + 2, bLd); }
        bf16x8 af[4][2], bfr[NJ][2];
#pragma unroll
        for (int kk = 0; kk < 2; ++kk) {
#pragma unroll
            for (int i = 0; i < 4; ++i)
                af[i][kk] = *(bf16x8*)(&As[aR + (wm + i * 16 + m) * 64 + (((kk * 4 + q) ^ (m & 7)) * 8)]);
#pragma unroll
            for (int j = 0; j < NJ; ++j)
                bfr[j][kk] = *(bf16x8*)(&Bs[bR + (wn + j * 16 + m) * 64 + (((kk * 4 + q) ^ (m & 7)) * 8)]);
        }
        if constexpr (NJ == 2) LGKM(6); else LGKM(5);   // wait kk=0 frags only
        SCHED0;
        __builtin_amdgcn_s_setprio(1);
#pragma unroll
        for (int i = 0; i < 4; ++i)
#pragma unroll
            for (int j = 0; j < NJ; ++j)
                acc[i][j] = __builtin_amdgcn_mfma_f32_16x16x32_bf16(af[i][0], bfr[j][0], acc[i][j], 0, 0, 0);
        LGKM(0); SCHED0;
#pragma unroll
        for (int i = 0; i < 4; ++i)
#pragma unroll
            for (int j = 0; j < NJ; ++j)
                acc[i][j] = __builtin_amdgcn_mfma_f32_16x16x32_bf16(af[i][1], bfr[j][1], acc[i][j], 0, 0, 0);
        __builtin_amdgcn_s_setprio(0);
        if (t + 1 < NSTEPS) {
            if (pf) { if constexpr (TN == 64) VMW(20); else VMW(12); }  // keep A(t+2)+B(t+2) in flight
            else    { VMW(0); }
            SCHED0;
            writeB(bW, bWr);
            LGKM(0);
        }
    };

    // prologue: A(0),A(1) DMA; B(0),B(1) -> regs; Bs0 <- B(0)
    issueA(0, 0u);
    issueA(1, 8192u);
    loadB(0, bA);
    loadB(1, bB);
    if constexpr (TN == 64) VMW(16); else VMW(8);   // A0,A1,B0 done; B1 in flight
    SCHED0;
    writeB(0u, bA);
    LGKM(0);

    unsigned aR = 0u, aM = 8192u, aW = 16384u;
    for (int t = 0; t < NSTEPS; t += 2) {
        STEP(t,     aR, aW, 0u,            (unsigned)BSE, bB, bA);
        { unsigned tp = aR; aR = aM; aM = aW; aW = tp; }
        STEP(t + 1, aR, aW, (unsigned)BSE, 0u,            bA, bB);
        { unsigned tp = aR; aR = aM; aM = aW; aW = tp; }
    }

    // epilogue: bias (+relu), store. D[row=q*4+r][col=m] per 16x16 subtile.
    const float* bp = bias + (size_t)e * N;
    int colbase = nt * TN + wn;
#pragma unroll
    for (int j = 0; j < NJ; ++j) {
        int col = colbase + j * 16 + m;
        float bv = bp[col];
#pragma unroll
        for (int i = 0; i < 4; ++i) {
            int rbase = row0 + wm + i * 16 + q * 4;
#pragma unroll
            for (int r = 0; r < 4; ++r) {
                float v = acc[i][j][r] + bv;
                if constexpr (RELU) v = fmaxf(v, 0.f);
                if constexpr (OUT_BF16)
                    ((__bf16*)OutV)[(size_t)(rbase + r) * N + col] = (__bf16)v;
                else
                    ((float*)OutV)[(size_t)(rbase + r) * N + col] = v;
            }
        }
    }
}

// ---------------- combine: out[b] = w0 * Y[r0] + w1 * Y[r1] (b3 folded into GEMM3) ----------------
__global__ __launch_bounds__(256) void combine_kernel(
    const float* __restrict__ Y, const int* __restrict__ off,
    const int* __restrict__ tok_e, const int* __restrict__ tok_p,
    const float* __restrict__ tok_w, float* __restrict__ out)
{
    int b = blockIdx.x, t = threadIdx.x;
    int e0 = tok_e[2 * b], e1 = tok_e[2 * b + 1];
    int r0 = off[e0] + tok_p[2 * b];
    int r1 = off[e1] + tok_p[2 * b + 1];
    float w0 = tok_w[2 * b], w1 = tok_w[2 * b + 1];
    int col = t * 4;
    f32x4 s0 = *(const f32x4*)(Y + (size_t)r0 * OO + col);
    f32x4 s1 = *(const f32x4*)(Y + (size_t)r1 * OO + col);
    f32x4 o = s0 * w0 + s1 * w1;
    *(f32x4*)(out + (size_t)b * OO + col) = o;
}

extern "C" void kernel_launch(void* const* d_in, const int* in_sizes, int n_in,
                              void* d_out, int out_size, void* d_ws, size_t ws_size,
                              hipStream_t stream)
{
    (void)in_sizes; (void)n_in; (void)out_size; (void)ws_size;
    const float* x  = (const float*)d_in[0];
    const float* Wr = (const float*)d_in[1];
    const float* br = (const float*)d_in[2];
    const float* W1 = (const float*)d_in[3];
    const float* b1 = (const float*)d_in[4];
    const float* W2 = (const float*)d_in[5];
    const float* b2 = (const float*)d_in[6];
    const float* W3 = (const float*)d_in[7];
    const float* b3 = (const float*)d_in[8];
    float* out = (float*)d_out;

    char* ws = (char*)d_ws;
    int*    counts = (int*)(ws + 0);
    int*    off    = (int*)(ws + 256);
    int*    tok_e  = (int*)(ws + 1024);
    int*    tok_p  = (int*)(ws + 9216);
    float*  tok_w  = (float*)(ws + 17408);
    int*    elist  = (int*)(ws + 25600);
    __bf16* Xg     = (__bf16*)(ws + 65536);
    __bf16* H1     = (__bf16*)(ws + 6356992);
    __bf16* H2     = (__bf16*)(ws + 18939904);
    float*  Y      = (float*)(ws + 31522816);

    hipMemsetAsync(counts, 0, 256, stream);
    router_kernel<<<1024, 256, 0, stream>>>(x, Wr, br, counts, elist, tok_e, tok_p, tok_w);
    offsets_kernel<<<1, 64, 0, stream>>>(counts, off);
    gather_kernel<<<dim3(32, 8), 256, 0, stream>>>(x, counts, off, elist, Xg);

    gemm_fused<1024, 2048, 64, true,  true ><<<dim3(256, 8), 256, 0, stream>>>(Xg, W1, b1, (void*)H1, counts, off);
    gemm_fused<2048, 2048, 64, true,  true ><<<dim3(256, 8), 256, 0, stream>>>(H1, W2, b2, (void*)H2, counts, off);
    gemm_fused<2048, 1024, 32, false, false><<<dim3(256, 8), 256, 0, stream>>>(H2, W3, b3, (void*)Y,  counts, off);

    combine_kernel<<<1024, 256, 0, stream>>>(Y, off, tok_e, tok_p, tok_w, out);
}